// Round 8
// baseline (193.761 us; speedup 1.0000x reference)
//
#include <hip/hip_runtime.h>

typedef _Float16 f16;
typedef __attribute__((ext_vector_type(8))) _Float16 f16x8;
typedef __attribute__((ext_vector_type(4))) float f32x4;

#define NSEQ 16
#define QL   128
#define NH   8
#define NG   4
#define DH   128
#define PGSZ 64
#define PPS  16
#define KT   64      // kv tile == page size (one scalar page lookup per tile)
#define QIB  32      // query indices per block
#define NQT  4
#define THR_DEFER 11.0f   // defer-max threshold in log2 domain (~7.6 nats)

// Barrier with LDS-visibility only (no vmcnt drain): in-flight global
// prefetch loads stay outstanding across it.
__device__ __forceinline__ void bar_lds() {
    asm volatile("s_waitcnt lgkmcnt(0)" ::: "memory");
    __builtin_amdgcn_s_barrier();
    asm volatile("" ::: "memory");
}

// DPP row_ror:N within 16-lane rows — cross-lane reduce on the VALU pipe.
template<int N>
__device__ __forceinline__ float rowror(float x) {
    int t = __builtin_amdgcn_update_dpp(__float_as_int(x), __float_as_int(x),
                                        0x120 | N, 0xF, 0xF, false);
    return __int_as_float(t);
}
__device__ __forceinline__ float rmax16(float x) {
    x = fmaxf(x, rowror<1>(x));
    x = fmaxf(x, rowror<2>(x));
    x = fmaxf(x, rowror<4>(x));
    x = fmaxf(x, rowror<8>(x));
    return x;
}
__device__ __forceinline__ float rsum16(float x) {
    x += rowror<1>(x);
    x += rowror<2>(x);
    x += rowror<4>(x);
    x += rowror<8>(x);
    return x;
}
__device__ __forceinline__ float fexp2(float x) {
    return __builtin_amdgcn_exp2f(x);
}

// Phase A: flash attention over a KV chunk of (16/NSPLIT) tiles.
// NSPLIT==1: writes normalized output directly.
// NSPLIT>1 : writes normalized partial O (f16) + per-row lse to workspace.
template<int NSPLIT>
__global__ __launch_bounds__(256, 2)
void rpa_fwd(const float* __restrict__ q,
             const float* __restrict__ kv_pages,
             const int* __restrict__ kv_lens,
             const int* __restrict__ page_indices,
             float* __restrict__ out,
             f16* __restrict__ wsO,
             float* __restrict__ wsL)
{
    constexpr int ZSH  = (NSPLIT == 4) ? 2 : (NSPLIT == 2 ? 1 : 0);
    constexpr int CMSK = NSPLIT - 1;
    constexpr int CHSH = 4 - ZSH;            // chunk size in tiles = 1<<CHSH

    const int tid  = threadIdx.x;
    const int w    = tid >> 6;    // wave 0..3, owns q-rows [w*32, w*32+32)
    const int lane = tid & 63;
    const int c16  = lane & 15;
    const int g16  = lane >> 4;

    const int qt = blockIdx.x;                // 0..3
    const int h  = blockIdx.y;                // 0..7
    const int s  = blockIdx.z >> ZSH;         // 0..15
    const int c  = blockIdx.z & CMSK;         // split id

    const int kv_len = kv_lens[s];
    const int kv_end = kv_len - QL + qt*QIB + QIB;   // exclusive kv bound
    const int ntile  = (kv_end + KT - 1) >> 6;
    const int tile0  = c << CHSH;
    const int tend   = min(tile0 + (1 << CHSH), ntile);
    const int p      = ((s*NQT + qt)*NH + h)*NSPLIT + c;   // partial index

    if (NSPLIT > 1 && tile0 >= ntile) {
        // empty split: weight-0 sentinel; O region left untouched (merge skips w==0)
        if (tid < 128) wsL[(size_t)p*128 + tid] = -1e30f;
        return;
    }

    // Un-padded rows + XOR slot swizzle (slot ^= row&7) -> conflict-free b128
    __shared__ f16 Klds [KT][DH];      // 64 rows x 256B
    __shared__ f16 VTlds[DH][KT];      // 128 rows x 128B (V transposed)
    __shared__ f16 Plds [4][QIB][KT];  // per-wave P, 32 rows x 128B

    // staging maps (256 threads)
    const int kr  = tid >> 2;          // K row 0..63
    const int kq  = (tid & 3) * 32;    // K f32 col base (32 floats/thread)
    const int vp  = tid & 31;          // V kv-pair -> kv = 2vp, 2vp+1
    const int vd0 = (tid >> 5) * 16;   // V d base (16 d/thread)

    // ---- Q fragments for 2 q-halves, pre-scaled by (1/sqrt(D))*log2(e)
    f16x8 qfrag[2][4];
    {
        const float sc = 0.08838834764831845f * 1.4426950408889634f;
        #pragma unroll
        for (int h2 = 0; h2 < 2; ++h2) {
            const int rowA = h2*16 + c16;
            const int qiA  = qt*QIB + w*8 + (rowA >> 2);
            const int gA   = rowA & 3;
            const float* qp = q + (((size_t)(s*QL + qiA)*NH + h)*NG + gA)*DH;
            #pragma unroll
            for (int sl = 0; sl < 4; ++sl) {
                const float* pp = qp + sl*32 + g16*8;
                f32x4 a = *(const f32x4*)pp;
                f32x4 b = *(const f32x4*)(pp + 4);
                f16x8 f;
                f[0]=(f16)(a[0]*sc); f[1]=(f16)(a[1]*sc); f[2]=(f16)(a[2]*sc); f[3]=(f16)(a[3]*sc);
                f[4]=(f16)(b[0]*sc); f[5]=(f16)(b[1]*sc); f[6]=(f16)(b[2]*sc); f[7]=(f16)(b[3]*sc);
                qfrag[h2][sl] = f;
            }
        }
    }

    // causal positions: D-frag row (h2,g16,r) -> qi = qt*32 + w*8 + h2*4 + g16
    int qp2[2];
    qp2[0] = kv_len - QL + qt*QIB + w*8 + g16;
    qp2[1] = qp2[0] + 4;
    const int qp_wave_min = kv_len - QL + qt*QIB + w*8;

    f32x4 oacc[2][8];
    #pragma unroll
    for (int h2 = 0; h2 < 2; ++h2)
        #pragma unroll
        for (int f = 0; f < 8; ++f) oacc[h2][f] = f32x4{0.f,0.f,0.f,0.f};
    float mrun[2][4], lrun[2][4];
    #pragma unroll
    for (int h2 = 0; h2 < 2; ++h2)
        #pragma unroll
        for (int r = 0; r < 4; ++r) { mrun[h2][r] = -1e30f; lrun[h2][r] = 0.f; }

    // prefetch regs: tile t+1 in flight across compute of tile t
    f32x4 kld[8], vld[8];

#define LOAD_TILE(T) do {                                                                \
        const int pg_ = page_indices[s*PPS + (T)];                                      \
        const float* kb_ = kv_pages + (((size_t)pg_*PGSZ + kr)*(2*NH) + h)*DH + kq;     \
        _Pragma("unroll")                                                                \
        for (int i_ = 0; i_ < 8; ++i_) kld[i_] = *(const f32x4*)(kb_ + i_*4);           \
        const float* vb_ = kv_pages + (((size_t)pg_*PGSZ + 2*vp)*(2*NH) + NH + h)*DH + vd0; \
        _Pragma("unroll")                                                                \
        for (int i_ = 0; i_ < 4; ++i_) vld[i_]   = *(const f32x4*)(vb_ + i_*4);         \
        _Pragma("unroll")                                                                \
        for (int i_ = 0; i_ < 4; ++i_) vld[4+i_] = *(const f32x4*)(vb_ + 2*NH*DH + i_*4); \
    } while (0)
    // rows >= kv_end stay within the page (valid memory) and are always causally masked.

#define WRITE_TILE() do {                                                                \
        _Pragma("unroll")                                                                \
        for (int i_ = 0; i_ < 4; ++i_) {                                                 \
            f16x8 kk_;                                                                   \
            _Pragma("unroll")                                                            \
            for (int j_ = 0; j_ < 4; ++j_) {                                             \
                kk_[j_]   = (f16)kld[2*i_][j_];                                          \
                kk_[4+j_] = (f16)kld[2*i_+1][j_];                                        \
            }                                                                            \
            const int slot_ = (((tid&3)*4 + i_) ^ (kr & 7));                             \
            *(f16x8*)((char*)&Klds[0][0] + kr*256 + (slot_<<4)) = kk_;                   \
        }                                                                                \
        _Pragma("unroll")                                                                \
        for (int j_ = 0; j_ < 16; ++j_) {                                                \
            union { f16 hh[2]; int u; } pk_;                                             \
            pk_.hh[0] = (f16)vld[j_>>2][j_&3];                                           \
            pk_.hh[1] = (f16)vld[4+(j_>>2)][j_&3];                                       \
            *(int*)((char*)&VTlds[0][0] + (vd0+j_)*128 + ((4*vp) ^ ((j_&7)<<4))) = pk_.u;\
        }                                                                                \
    } while (0)

    LOAD_TILE(tile0);

    for (int t = tile0; t < tend; ++t) {
        const int kv0 = t << 6;

        WRITE_TILE();                     // vmcnt waits on prefetch regs here
        bar_lds();                        // stage visible; globals stay in flight
        if (t + 1 < tend) LOAD_TILE(t+1); // issue next tile, hidden under compute

        // ---- QK^T: 32 q-rows x 64 kv; 16 K reads shared across both q-halves
        f32x4 sacc[2][4];
        #pragma unroll
        for (int h2 = 0; h2 < 2; ++h2)
            #pragma unroll
            for (int ks = 0; ks < 4; ++ks) sacc[h2][ks] = f32x4{0.f,0.f,0.f,0.f};
        #pragma unroll
        for (int ks = 0; ks < 4; ++ks) {
            #pragma unroll
            for (int sl = 0; sl < 4; ++sl) {
                f16x8 kf = *(const f16x8*)((const char*)&Klds[0][0]
                            + (ks*16 + c16)*256 + ((((sl<<2)|g16) ^ (c16&7))<<4));
                sacc[0][ks] = __builtin_amdgcn_mfma_f32_16x16x32_f16(qfrag[0][sl], kf, sacc[0][ks], 0,0,0);
                sacc[1][ks] = __builtin_amdgcn_mfma_f32_16x16x32_f16(qfrag[1][sl], kf, sacc[1][ks], 0,0,0);
            }
        }

        // ---- causal mask (wave-uniform skip for interior tiles)
        if (kv0 + KT - 1 > qp_wave_min) {
            #pragma unroll
            for (int h2 = 0; h2 < 2; ++h2)
                #pragma unroll
                for (int ks = 0; ks < 4; ++ks) {
                    const bool ok = (kv0 + ks*16 + c16) <= qp2[h2];
                    #pragma unroll
                    for (int r = 0; r < 4; ++r)
                        sacc[h2][ks][r] = ok ? sacc[h2][ks][r] : -1e30f;
                }
        }

        // ---- online softmax (exp2 domain), DPP reduces, defer-max rescale.
        // Dead rows (fully masked so far): mt=-1e30, m stays -1e30, p=exp2(0)=1
        // junk accumulates BUT first live tile forces rescale with fac=0 (wipe);
        // rows dead through the whole split export lse=-1e30 -> merge weight 0.
        float mt[2][4];
        bool need = false;
        #pragma unroll
        for (int h2 = 0; h2 < 2; ++h2)
            #pragma unroll
            for (int r = 0; r < 4; ++r) {
                float a = fmaxf(fmaxf(sacc[h2][0][r], sacc[h2][1][r]),
                                fmaxf(sacc[h2][2][r], sacc[h2][3][r]));
                a = rmax16(a);
                mt[h2][r] = a;
                need = need || (a > mrun[h2][r] + THR_DEFER);
            }
        if (__any(need)) {
            #pragma unroll
            for (int h2 = 0; h2 < 2; ++h2)
                #pragma unroll
                for (int r = 0; r < 4; ++r) {
                    const float mn  = fmaxf(mrun[h2][r], mt[h2][r]);
                    const float fac = fexp2(mrun[h2][r] - mn);
                    lrun[h2][r] *= fac;
                    mrun[h2][r] = mn;
                    #pragma unroll
                    for (int f = 0; f < 8; ++f) oacc[h2][f] *= fac;
                }
        }
        #pragma unroll
        for (int h2 = 0; h2 < 2; ++h2)
            #pragma unroll
            for (int r = 0; r < 4; ++r) {
                const float m = mrun[h2][r];
                float p0 = fexp2(sacc[h2][0][r] - m);
                float p1 = fexp2(sacc[h2][1][r] - m);
                float p2 = fexp2(sacc[h2][2][r] - m);
                float p3 = fexp2(sacc[h2][3][r] - m);
                lrun[h2][r] += rsum16((p0 + p1) + (p2 + p3));
                const int prow = h2*16 + g16*4 + r;
                char* pb = (char*)&Plds[w][0][0] + prow*128;
                const int key = (prow & 7) << 4;
                *(f16*)(pb + ((0*32 + 2*c16) ^ key)) = (f16)p0;
                *(f16*)(pb + ((1*32 + 2*c16) ^ key)) = (f16)p1;
                *(f16*)(pb + ((2*32 + 2*c16) ^ key)) = (f16)p2;
                *(f16*)(pb + ((3*32 + 2*c16) ^ key)) = (f16)p3;
            }

        // ---- P @ V: 16 V reads shared across both q-halves
        #pragma unroll
        for (int kvh = 0; kvh < 2; ++kvh) {
            f16x8 pf0 = *(const f16x8*)((const char*)&Plds[w][0][0]
                         + (0*16 + c16)*128 + ((((kvh<<2)|g16) ^ (c16&7))<<4));
            f16x8 pf1 = *(const f16x8*)((const char*)&Plds[w][0][0]
                         + (1*16 + c16)*128 + ((((kvh<<2)|g16) ^ (c16&7))<<4));
            #pragma unroll
            for (int f = 0; f < 8; ++f) {
                f16x8 vf = *(const f16x8*)((const char*)&VTlds[0][0]
                            + (f*16 + c16)*128 + ((((kvh<<2)|g16) ^ (c16&7))<<4));
                oacc[0][f] = __builtin_amdgcn_mfma_f32_16x16x32_f16(pf0, vf, oacc[0][f], 0,0,0);
                oacc[1][f] = __builtin_amdgcn_mfma_f32_16x16x32_f16(pf1, vf, oacc[1][f], 0,0,0);
            }
        }

        bar_lds();   // all reads of K/VT done before next WRITE_TILE
    }

    // ---- epilogue
    #pragma unroll
    for (int h2 = 0; h2 < 2; ++h2) {
        #pragma unroll
        for (int r = 0; r < 4; ++r) {
            const float l   = lrun[h2][r];
            const float inv = 1.f / fmaxf(l, 1e-10f);
            if (NSPLIT > 1) {
                const int row = (w*8 + h2*4 + g16)*4 + r;   // qi_local*4 + g
                if (c16 == 0)
                    wsL[(size_t)p*128 + row] = mrun[h2][r] + __log2f(fmaxf(l, 1e-10f));
                f16* ob = wsO + (size_t)p*16384 + row*128;
                #pragma unroll
                for (int f = 0; f < 8; ++f)
                    ob[f*16 + c16] = (f16)(oacc[h2][f][r] * inv);
            } else {
                const int qi = qt*QIB + w*8 + h2*4 + g16;
                float* op = out + (((size_t)(s*QL + qi)*NH + h)*NG + r)*DH;
                #pragma unroll
                for (int f = 0; f < 8; ++f)
                    op[f*16 + c16] = oacc[h2][f][r] * inv;
            }
        }
    }
}

// Phase B: merge NSPLIT partials. out = sum_c w_c*O_c / sum_c w_c,
// w_c = 2^(lse_c - lse_max). Skips w==0 partials (never touches their O).
template<int NSPLIT>
__global__ __launch_bounds__(256)
void rpa_merge(const f16* __restrict__ wsO, const float* __restrict__ wsL,
               float* __restrict__ out)
{
    const int tid = threadIdx.x;
    const int qt = blockIdx.x, h = blockIdx.y, s = blockIdx.z;
    const int row = tid >> 1;          // 0..127 = qi_local*4 + g
    const int dh  = (tid & 1) * 64;
    const int p0  = ((s*NQT + qt)*NH + h) * NSPLIT;

    float wgt[NSPLIT];
    float lmax = -3.0e38f;
    #pragma unroll
    for (int c = 0; c < NSPLIT; ++c) {
        wgt[c] = wsL[(size_t)(p0 + c)*128 + row];
        lmax = fmaxf(lmax, wgt[c]);
    }
    float den = 0.f;
    #pragma unroll
    for (int c = 0; c < NSPLIT; ++c) {
        wgt[c] = fexp2(wgt[c] - lmax);
        den += wgt[c];
    }
    const float rden = 1.f / den;   // den >= 1 (split 0 is always live per row)

    const int qi = qt*QIB + (row >> 2);
    const int g  = row & 3;
    float* op = out + (((size_t)(s*QL + qi)*NH + h)*NG + g)*DH + dh;
    const f16* ob = wsO + (size_t)p0*16384 + row*128 + dh;

    #pragma unroll
    for (int f = 0; f < 8; ++f) {
        float acc[8] = {0.f,0.f,0.f,0.f,0.f,0.f,0.f,0.f};
        #pragma unroll
        for (int c = 0; c < NSPLIT; ++c) {
            if (wgt[c] != 0.f) {
                f16x8 v = *(const f16x8*)(ob + (size_t)c*16384 + f*8);
                #pragma unroll
                for (int j = 0; j < 8; ++j)
                    acc[j] = fmaf((float)v[j], wgt[c], acc[j]);
            }
        }
        #pragma unroll
        for (int j = 0; j < 8; ++j)
            op[f*8 + j] = acc[j] * rden;
    }
}

extern "C" void kernel_launch(void* const* d_in, const int* in_sizes, int n_in,
                              void* d_out, int out_size, void* d_ws, size_t ws_size,
                              hipStream_t stream) {
    (void)in_sizes; (void)n_in; (void)out_size;
    const float* q         = (const float*)d_in[0];
    const float* kv_pages  = (const float*)d_in[1];
    const int*   kv_lens   = (const int*)d_in[2];
    const int*   page_idx  = (const int*)d_in[3];
    float* out = (float*)d_out;

    // workspace: [512*nsplit] partials x (O: 128x128 f16 = 32768 B, lse: 128 f32 = 512 B)
    const size_t need4 = (size_t)512 * 4 * (32768 + 512);
    const size_t need2 = (size_t)512 * 2 * (32768 + 512);

    if (ws_size >= need4) {
        f16*   wsO = (f16*)d_ws;
        float* wsL = (float*)((char*)d_ws + (size_t)512*4*32768);
        dim3 gA(NQT, NH, NSEQ*4);
        rpa_fwd<4><<<gA, 256, 0, stream>>>(q, kv_pages, kv_lens, page_idx, out, wsO, wsL);
        dim3 gM(NQT, NH, NSEQ);
        rpa_merge<4><<<gM, 256, 0, stream>>>(wsO, wsL, out);
    } else if (ws_size >= need2) {
        f16*   wsO = (f16*)d_ws;
        float* wsL = (float*)((char*)d_ws + (size_t)512*2*32768);
        dim3 gA(NQT, NH, NSEQ*2);
        rpa_fwd<2><<<gA, 256, 0, stream>>>(q, kv_pages, kv_lens, page_idx, out, wsO, wsL);
        dim3 gM(NQT, NH, NSEQ);
        rpa_merge<2><<<gM, 256, 0, stream>>>(wsO, wsL, out);
    } else {
        dim3 gA(NQT, NH, NSEQ);
        rpa_fwd<1><<<gA, 256, 0, stream>>>(q, kv_pages, kv_lens, page_idx, out, nullptr, nullptr);
    }
}

// Round 9
// 112.064 us; speedup vs baseline: 1.7290x; 1.7290x over previous
//
#include <hip/hip_runtime.h>

typedef _Float16 f16;
typedef __attribute__((ext_vector_type(8))) _Float16 f16x8;
typedef __attribute__((ext_vector_type(4))) float f32x4;

#define NSEQ 16
#define QL   128
#define NH   8
#define NG   4
#define DH   128
#define PGSZ 64
#define PPS  16
#define KT   32      // kv tile
#define QIB  32      // query indices per block
#define NQT  (QL / QIB)
#define NWAVE 8
#define KPAD 8       // K row stride 272B -> banks rotate by 4, 2-way max (free)
#define VPAD 8       // VT/P row stride 80B -> banks rotate by 20, 2-way max (free)
#define THR_DEFER 11.0f   // defer-max threshold, log2 domain (~7.6 nats)

// Barrier with LDS-visibility only (no vmcnt drain): in-flight global
// prefetch loads stay outstanding across it.
__device__ __forceinline__ void bar_lds() {
    asm volatile("s_waitcnt lgkmcnt(0)" ::: "memory");
    __builtin_amdgcn_s_barrier();
    asm volatile("" ::: "memory");
}

// DPP row_ror:N within 16-lane rows — cross-lane reduce on the VALU pipe
// (reduce is over c16 lanes = one DPP row; zero DS-pipe traffic).
template<int N>
__device__ __forceinline__ float rowror(float x) {
    int t = __builtin_amdgcn_update_dpp(__float_as_int(x), __float_as_int(x),
                                        0x120 | N, 0xF, 0xF, false);
    return __int_as_float(t);
}
__device__ __forceinline__ float rmax16(float x) {
    x = fmaxf(x, rowror<1>(x));
    x = fmaxf(x, rowror<2>(x));
    x = fmaxf(x, rowror<4>(x));
    x = fmaxf(x, rowror<8>(x));
    return x;
}
__device__ __forceinline__ float rsum16(float x) {
    x += rowror<1>(x);
    x += rowror<2>(x);
    x += rowror<4>(x);
    x += rowror<8>(x);
    return x;
}
__device__ __forceinline__ float fexp2(float x) {
    return __builtin_amdgcn_exp2f(x);
}

// Phase A: R2 structure (8 waves, KT=32, padded LDS, dbuf) + KV split.
// NSPLIT==1 writes normalized output; NSPLIT>1 writes normalized partial O
// (f16) + per-row lse (log2 domain) to workspace.
template<int NSPLIT>
__global__ __launch_bounds__(512, 2)
void rpa_fwd(const float* __restrict__ q,
             const float* __restrict__ kv_pages,
             const int* __restrict__ kv_lens,
             const int* __restrict__ page_indices,
             float* __restrict__ out,
             f16* __restrict__ wsO,
             float* __restrict__ wsL)
{
    constexpr int ZSH  = (NSPLIT == 4) ? 2 : (NSPLIT == 2 ? 1 : 0);
    constexpr int CMSK = NSPLIT - 1;
    constexpr int CHSH = 5 - ZSH;           // chunk size in KT-tiles = 1<<CHSH

    const int tid  = threadIdx.x;
    const int wave = tid >> 6;
    const int lane = tid & 63;
    const int c16  = lane & 15;
    const int g16  = lane >> 4;

    const int qt = blockIdx.x;                // 0..3
    const int h  = blockIdx.y;                // 0..7
    const int s  = blockIdx.z >> ZSH;         // 0..15
    const int c  = blockIdx.z & CMSK;         // split id

    const int kv_len = kv_lens[s];
    const int kv_end = kv_len - QL + qt*QIB + QIB;   // exclusive kv bound
    const int ntile  = (kv_end + KT - 1) / KT;       // <= 32
    const int tile0  = c << CHSH;
    const int tend   = min(tile0 + (1 << CHSH), ntile);
    const int p      = ((s*NQT + qt)*NH + h)*NSPLIT + c;

    if (NSPLIT > 1 && tile0 >= ntile) {
        // empty split: weight-0 sentinel; O region untouched (merge skips w==0)
        if (tid < 128) wsL[(size_t)p*128 + tid] = -1e30f;
        return;
    }

    __shared__ f16 Klds [2][KT][DH + KPAD];
    __shared__ f16 VTlds[2][DH][KT + VPAD];
    __shared__ f16 Plds [NWAVE][16][KT + VPAD];

    // staging thread mapping (whole block cooperates)
    const int krow = tid >> 4;          // 0..31  (kv row for K)
    const int kd0  = (tid & 15) * 8;    // 0..120 (d offset for K, 8 elems)
    const int vkp2 = tid & 15;          // kv pair index for V -> kv = 2vkp2, +1
    const int vd0  = (tid >> 4) * 4;    // 0..124 (d offset for V, 4 elems)

    // ---- Q fragments (A-layout): row=c16, k(d)=sl*32+g16*8+j.
    // Pre-scaled by (1/sqrt(D))*log2(e) for exp2-domain softmax.
    f16x8 qfrag[4];
    {
        const int rowA = c16;
        const int qiA  = qt*QIB + wave*4 + (rowA >> 2);
        const int gA   = rowA & 3;
        const int tA   = s*QL + qiA;
        const float* qp = q + (((size_t)tA*NH + h)*NG + gA)*DH;
        const float sc = 0.08838834764831845f * 1.4426950408889634f;
        #pragma unroll
        for (int sl = 0; sl < 4; ++sl) {
            const float* pp = qp + sl*32 + g16*8;
            f32x4 a = *(const f32x4*)pp;
            f32x4 b = *(const f32x4*)(pp + 4);
            f16x8 f;
            f[0]=(f16)(a[0]*sc); f[1]=(f16)(a[1]*sc); f[2]=(f16)(a[2]*sc); f[3]=(f16)(a[3]*sc);
            f[4]=(f16)(b[0]*sc); f[5]=(f16)(b[1]*sc); f[6]=(f16)(b[2]*sc); f[7]=(f16)(b[3]*sc);
            qfrag[sl] = f;
        }
    }

    // D-frag rows: row = g16*4 + r -> qi = qt*QIB + wave*4 + g16, g = r
    const int qi_loc = wave*4 + g16;                 // local qi in [0,32)
    const int q_pos  = kv_len - QL + qt*QIB + qi_loc;
    const int qp_wave_min = kv_len - QL + qt*QIB + wave*4;

    f32x4 oacc[8];
    #pragma unroll
    for (int f = 0; f < 8; ++f) oacc[f] = f32x4{0.f, 0.f, 0.f, 0.f};
    float mrun[4] = {-1e30f, -1e30f, -1e30f, -1e30f};
    float lrun[4] = {0.f, 0.f, 0.f, 0.f};

    // prefetch registers (tile t+1 in flight while computing tile t)
    f32x4 ka, kb, va, vb;

#define LOAD_TILE(KV0) do {                                                              \
        ka = f32x4{0.f,0.f,0.f,0.f}; kb = ka; va = ka; vb = ka;                          \
        const int kvp_ = (KV0) + krow;                                                   \
        if (kvp_ < kv_end) {                                                             \
            const int pg_ = page_indices[s*PPS + (kvp_ >> 6)];                           \
            const float* kp_ = kv_pages +                                                \
                ((((size_t)pg_*PGSZ) + (kvp_ & (PGSZ-1)))*(2*NH) + h)*DH + kd0;          \
            ka = *(const f32x4*)kp_; kb = *(const f32x4*)(kp_ + 4);                      \
        }                                                                                \
        const int kva_ = (KV0) + 2*vkp2;                                                 \
        if (kva_ < kv_end) {                                                             \
            const int pg_ = page_indices[s*PPS + (kva_ >> 6)];                           \
            va = *(const f32x4*)(kv_pages +                                              \
                ((((size_t)pg_*PGSZ) + (kva_ & (PGSZ-1)))*(2*NH) + NH + h)*DH + vd0);    \
        }                                                                                \
        const int kvb_ = (KV0) + 2*vkp2 + 1;                                             \
        if (kvb_ < kv_end) {                                                             \
            const int pg_ = page_indices[s*PPS + (kvb_ >> 6)];                           \
            vb = *(const f32x4*)(kv_pages +                                              \
                ((((size_t)pg_*PGSZ) + (kvb_ & (PGSZ-1)))*(2*NH) + NH + h)*DH + vd0);    \
        }                                                                                \
    } while (0)

#define WRITE_TILE(BUF) do {                                                             \
        f16x8 kk_;                                                                       \
        kk_[0]=(f16)ka[0]; kk_[1]=(f16)ka[1]; kk_[2]=(f16)ka[2]; kk_[3]=(f16)ka[3];      \
        kk_[4]=(f16)kb[0]; kk_[5]=(f16)kb[1]; kk_[6]=(f16)kb[2]; kk_[7]=(f16)kb[3];      \
        *(f16x8*)&Klds[BUF][krow][kd0] = kk_;                                            \
        _Pragma("unroll")                                                                \
        for (int j_ = 0; j_ < 4; ++j_) {                                                 \
            union { f16 hh[2]; unsigned u; } pk_;                                        \
            pk_.hh[0] = (f16)va[j_];                                                     \
            pk_.hh[1] = (f16)vb[j_];                                                     \
            *(unsigned*)&VTlds[BUF][vd0 + j_][2*vkp2] = pk_.u;                           \
        }                                                                                \
    } while (0)

    LOAD_TILE(tile0 * KT);
    int buf = 0;

    for (int t = tile0; t < tend; ++t) {
        const int kv0 = t * KT;

        WRITE_TILE(buf);                           // vmcnt waits on prefetch regs
        if (t + 1 < tend) LOAD_TILE(kv0 + KT);     // next tile into flight
        bar_lds();                                 // LDS visible; globals in flight

        // ---- QK^T: S[16 rows][32 kv]
        f32x4 sacc[2];
        sacc[0] = f32x4{0.f,0.f,0.f,0.f};
        sacc[1] = f32x4{0.f,0.f,0.f,0.f};
        #pragma unroll
        for (int ks = 0; ks < 2; ++ks) {
            #pragma unroll
            for (int sl = 0; sl < 4; ++sl) {
                f16x8 kf = *(const f16x8*)&Klds[buf][ks*16 + c16][sl*32 + g16*8];
                sacc[ks] = __builtin_amdgcn_mfma_f32_16x16x32_f16(qfrag[sl], kf, sacc[ks], 0, 0, 0);
            }
        }

        // ---- causal mask (wave-uniform skip for interior tiles)
        if (kv0 + KT - 1 > qp_wave_min) {
            const bool ok0 = (kv0 + c16)      <= q_pos;
            const bool ok1 = (kv0 + 16 + c16) <= q_pos;
            #pragma unroll
            for (int r = 0; r < 4; ++r) {
                sacc[0][r] = ok0 ? sacc[0][r] : -1e30f;
                sacc[1][r] = ok1 ? sacc[1][r] : -1e30f;
            }
        }

        // ---- online softmax (exp2 domain), DPP reduces, defer-max rescale.
        // Rows dead so far: m stays -1e30, junk p=1 accumulates; first live
        // tile forces rescale fac=exp2(-inf)=0 -> wipe. Rows dead all split
        // export lse=-1e30 -> merge weight 0.
        float mt[4];
        bool need = false;
        #pragma unroll
        for (int r = 0; r < 4; ++r) {
            float a = fmaxf(sacc[0][r], sacc[1][r]);
            a = rmax16(a);
            mt[r] = a;
            need = need || (a > mrun[r] + THR_DEFER);
        }
        if (__any(need)) {
            #pragma unroll
            for (int r = 0; r < 4; ++r) {
                const float mn  = fmaxf(mrun[r], mt[r]);
                const float fac = fexp2(mrun[r] - mn);
                lrun[r] *= fac;
                mrun[r] = mn;
                #pragma unroll
                for (int f = 0; f < 8; ++f) oacc[f][r] *= fac;
            }
        }
        #pragma unroll
        for (int r = 0; r < 4; ++r) {
            const float p0 = fexp2(sacc[0][r] - mrun[r]);
            const float p1 = fexp2(sacc[1][r] - mrun[r]);
            lrun[r] += rsum16(p0 + p1);
            Plds[wave][g16*4 + r][c16]      = (f16)p0;
            Plds[wave][g16*4 + r][16 + c16] = (f16)p1;
        }
        // no barrier — Plds[wave] is wave-private; DS pipe is in-order per wave

        // ---- P @ V
        f16x8 pf = *(const f16x8*)&Plds[wave][c16][g16*8];
        #pragma unroll
        for (int f = 0; f < 8; ++f) {
            f16x8 vf = *(const f16x8*)&VTlds[buf][f*16 + c16][g16*8];
            oacc[f] = __builtin_amdgcn_mfma_f32_16x16x32_f16(pf, vf, oacc[f], 0, 0, 0);
        }
        buf ^= 1;
        // no trailing barrier: reads of buf are lgkm-drained at next bar_lds();
        // writes to buf resume only one iteration later
    }

    // ---- epilogue
    #pragma unroll
    for (int r = 0; r < 4; ++r) {
        const float l   = lrun[r];
        const float inv = 1.f / fmaxf(l, 1e-10f);
        if (NSPLIT > 1) {
            const int row = qi_loc*4 + r;      // local row in [0,128)
            if (c16 == 0)
                wsL[(size_t)p*128 + row] = mrun[r] + __log2f(fmaxf(l, 1e-10f));
            f16* ob = wsO + (size_t)p*16384 + row*128;
            #pragma unroll
            for (int f = 0; f < 8; ++f)
                ob[f*16 + c16] = (f16)(oacc[f][r] * inv);
        } else {
            const int qi = qt*QIB + qi_loc;
            float* op = out + (((size_t)(s*QL + qi)*NH + h)*NG + r)*DH;
            #pragma unroll
            for (int f = 0; f < 8; ++f)
                op[f*16 + c16] = oacc[f][r] * inv;
        }
    }
}

// Phase B: merge NSPLIT partials. out = sum_c w_c*O_c / sum_c w_c,
// w_c = 2^(lse_c - lse_max). Skips w==0 partials (never touches their O).
template<int NSPLIT>
__global__ __launch_bounds__(256)
void rpa_merge(const f16* __restrict__ wsO, const float* __restrict__ wsL,
               float* __restrict__ out)
{
    const int tid = threadIdx.x;
    const int qt = blockIdx.x, h = blockIdx.y, s = blockIdx.z;
    const int row = tid >> 1;          // 0..127 = qi_local*4 + g
    const int dh  = (tid & 1) * 64;
    const int p0  = ((s*NQT + qt)*NH + h) * NSPLIT;

    float wgt[NSPLIT];
    float lmax = -3.0e38f;
    #pragma unroll
    for (int c = 0; c < NSPLIT; ++c) {
        wgt[c] = wsL[(size_t)(p0 + c)*128 + row];
        lmax = fmaxf(lmax, wgt[c]);
    }
    float den = 0.f;
    #pragma unroll
    for (int c = 0; c < NSPLIT; ++c) {
        wgt[c] = fexp2(wgt[c] - lmax);
        den += wgt[c];
    }
    const float rden = 1.f / den;   // den >= 1 (the lmax split has weight 1)

    const int qi = qt*QIB + (row >> 2);
    const int g  = row & 3;
    float* op = out + (((size_t)(s*QL + qi)*NH + h)*NG + g)*DH + dh;
    const f16* ob = wsO + (size_t)p0*16384 + row*128 + dh;

    #pragma unroll
    for (int f = 0; f < 8; ++f) {
        float acc[8] = {0.f,0.f,0.f,0.f,0.f,0.f,0.f,0.f};
        #pragma unroll
        for (int c = 0; c < NSPLIT; ++c) {
            if (wgt[c] != 0.f) {
                f16x8 v = *(const f16x8*)(ob + (size_t)c*16384 + f*8);
                #pragma unroll
                for (int j = 0; j < 8; ++j)
                    acc[j] = fmaf((float)v[j], wgt[c], acc[j]);
            }
        }
        #pragma unroll
        for (int j = 0; j < 8; ++j)
            op[f*8 + j] = acc[j] * rden;
    }
}

extern "C" void kernel_launch(void* const* d_in, const int* in_sizes, int n_in,
                              void* d_out, int out_size, void* d_ws, size_t ws_size,
                              hipStream_t stream) {
    (void)in_sizes; (void)n_in; (void)out_size;
    const float* q         = (const float*)d_in[0];
    const float* kv_pages  = (const float*)d_in[1];
    const int*   kv_lens   = (const int*)d_in[2];
    const int*   page_idx  = (const int*)d_in[3];
    float* out = (float*)d_out;

    // workspace per partial: O 128x128 f16 = 32768 B, lse 128 f32 = 512 B
    const size_t need2 = (size_t)512 * 2 * (32768 + 512);

    if (ws_size >= need2) {
        // NSPLIT=2: 1024 blocks x 8 waves -> up to 3 blocks/CU (LDS-capped),
        // ~24 waves/CU vs R2's grid-capped 16.
        f16*   wsO = (f16*)d_ws;
        float* wsL = (float*)((char*)d_ws + (size_t)512*2*32768);
        dim3 gA(NQT, NH, NSEQ*2);
        rpa_fwd<2><<<gA, 512, 0, stream>>>(q, kv_pages, kv_lens, page_idx, out, wsO, wsL);
        dim3 gM(NQT, NH, NSEQ);
        rpa_merge<2><<<gM, 256, 0, stream>>>(wsO, wsL, out);
    } else {
        dim3 gA(NQT, NH, NSEQ);
        rpa_fwd<1><<<gA, 512, 0, stream>>>(q, kv_pages, kv_lens, page_idx, out, nullptr, nullptr);
    }
}